// Round 3
// baseline (126.827 us; speedup 1.0000x reference)
//
#include <hip/hip_runtime.h>
#include <hip/hip_bf16.h>

// out[n,h] = x[n,h] * weight[h] + bias[h]
// N=16384, H=4096, fp32 in/out. Pure streaming.
// (grid*block) % (H/4) == 0 by construction, so each thread's per-float4
// feature index h4 = tid & (H/4-1) is loop-invariant -> w/b hoisted into
// registers. x/out touched exactly once -> non-temporal loads/stores.
// Unroll x4 for load-queue ILP.
//
// NOTE: __builtin_nontemporal_* requires native clang vector types, not
// HIP_vector_type structs -> use ext_vector_type(4) float.

typedef float v4f __attribute__((ext_vector_type(4)));

__global__ __launch_bounds__(256) void scale_shift_f32_hoist(
    const v4f* __restrict__ x,
    const v4f* __restrict__ w,
    const v4f* __restrict__ b,
    v4f* __restrict__ out,
    int total4, int h4mask) {
    const int tid = blockIdx.x * blockDim.x + threadIdx.x;
    const int stride = gridDim.x * blockDim.x;   // host guarantees: multiple of (h4mask+1)

    const int h4 = tid & h4mask;                 // loop-invariant by construction
    const v4f wv = w[h4];
    const v4f bv = b[h4];

    int i = tid;
    // main loop: 4 independent loads in flight before any store
    for (; i + 3 * stride < total4; i += 4 * stride) {
        v4f x0 = __builtin_nontemporal_load(&x[i]);
        v4f x1 = __builtin_nontemporal_load(&x[i + stride]);
        v4f x2 = __builtin_nontemporal_load(&x[i + 2 * stride]);
        v4f x3 = __builtin_nontemporal_load(&x[i + 3 * stride]);

        v4f o0 = x0 * wv + bv;
        v4f o1 = x1 * wv + bv;
        v4f o2 = x2 * wv + bv;
        v4f o3 = x3 * wv + bv;

        __builtin_nontemporal_store(o0, &out[i]);
        __builtin_nontemporal_store(o1, &out[i + stride]);
        __builtin_nontemporal_store(o2, &out[i + 2 * stride]);
        __builtin_nontemporal_store(o3, &out[i + 3 * stride]);
    }
    // tail
    for (; i < total4; i += stride) {
        v4f xv = __builtin_nontemporal_load(&x[i]);
        v4f o = xv * wv + bv;
        __builtin_nontemporal_store(o, &out[i]);
    }
}

extern "C" void kernel_launch(void* const* d_in, const int* in_sizes, int n_in,
                              void* d_out, int out_size, void* d_ws, size_t ws_size,
                              hipStream_t stream) {
    const float* x = (const float*)d_in[0];
    const float* w = (const float*)d_in[1];
    const float* b = (const float*)d_in[2];
    float* out = (float*)d_out;

    const int H = in_sizes[1];           // 4096
    const int total = out_size;          // N*H = 67,108,864
    const int total4 = total / 4;
    const int h4 = H / 4;                // 1024, power of two
    const int h4mask = h4 - 1;

    const int block = 256;
    // grid*block must be a multiple of h4 so the h4-index is thread-invariant.
    int grid = 2048;                     // 2048*256 = 524288 = 512*1024
    while ((long long)grid * block % h4 != 0 && grid > 1) grid--;

    scale_shift_f32_hoist<<<grid, block, 0, stream>>>(
        (const v4f*)x, (const v4f*)w, (const v4f*)b,
        (v4f*)out, total4, h4mask);
}

// Round 4
// 110.019 us; speedup vs baseline: 1.1528x; 1.1528x over previous
//
#include <hip/hip_runtime.h>
#include <hip/hip_bf16.h>

// out[n,h] = x[n,h] * weight[h] + bias[h]
// N=16384, H=4096, fp32 in/out. Pure streaming.
// (grid*block) % (H/4) == 0 by construction -> per-thread feature index
// h4 = tid & (H/4-1) is loop-invariant -> w/b hoisted into registers.
// NO non-temporal hints (R3 showed nt stores regress 107->127 us: they
// bypass L2's write-coalescing in front of HBM). Mild x2 unroll for ILP.

typedef float v4f __attribute__((ext_vector_type(4)));

__global__ __launch_bounds__(256) void scale_shift_f32_hoist(
    const v4f* __restrict__ x,
    const v4f* __restrict__ w,
    const v4f* __restrict__ b,
    v4f* __restrict__ out,
    int total4, int h4mask) {
    const int tid = blockIdx.x * blockDim.x + threadIdx.x;
    const int stride = gridDim.x * blockDim.x;   // host guarantees: multiple of (h4mask+1)

    const int h4 = tid & h4mask;                 // loop-invariant by construction
    const v4f wv = w[h4];
    const v4f bv = b[h4];

    int i = tid;
    // x2 unroll: two independent loads in flight before the stores
    for (; i + stride < total4; i += 2 * stride) {
        v4f x0 = x[i];
        v4f x1 = x[i + stride];
        v4f o0 = x0 * wv + bv;
        v4f o1 = x1 * wv + bv;
        out[i] = o0;
        out[i + stride] = o1;
    }
    for (; i < total4; i += stride) {
        out[i] = x[i] * wv + bv;
    }
}

extern "C" void kernel_launch(void* const* d_in, const int* in_sizes, int n_in,
                              void* d_out, int out_size, void* d_ws, size_t ws_size,
                              hipStream_t stream) {
    const float* x = (const float*)d_in[0];
    const float* w = (const float*)d_in[1];
    const float* b = (const float*)d_in[2];
    float* out = (float*)d_out;

    const int H = in_sizes[1];           // 4096
    const int total = out_size;          // N*H = 67,108,864
    const int total4 = total / 4;
    const int h4 = H / 4;                // 1024, power of two
    const int h4mask = h4 - 1;

    const int block = 256;
    // grid*block must be a multiple of h4 so the h4-index is thread-invariant.
    int grid = 2048;                     // 2048*256 = 524288 = 512*1024
    while ((long long)grid * block % h4 != 0 && grid > 1) grid--;

    scale_shift_f32_hoist<<<grid, block, 0, stream>>>(
        (const v4f*)x, (const v4f*)w, (const v4f*)b,
        (v4f*)out, total4, h4mask);
}